// Round 1
// baseline (172.865 us; speedup 1.0000x reference)
//
#include <hip/hip_runtime.h>
#include <hip/hip_bf16.h>

#define BATCH 16
#define CH    256
#define HW    1024
#define NH    4
#define DH    64
#define NG    32
#define CPG   8
#define EPSV  1e-6f

// log2(e) / sqrt(C) folded into Q so softmax = exp2(S_scaled)
#define QSCALE 0.090168440055558706f

typedef __bf16 bf16x8 __attribute__((ext_vector_type(8)));
typedef float  f32x4  __attribute__((ext_vector_type(4)));

__device__ __forceinline__ unsigned short f2bf(float f) {
    union { __hip_bfloat16 h; unsigned short u; } cv;
    cv.h = __float2bfloat16(f);
    return cv.u;
}

__device__ __forceinline__ unsigned int fbits(float f) {
    union { float f; unsigned int u; } cv; cv.f = f; return cv.u;
}

__device__ __forceinline__ void gld_lds16(const unsigned short* g, unsigned short* l) {
    __builtin_amdgcn_global_load_lds(
        (const __attribute__((address_space(1))) void*)g,
        (__attribute__((address_space(3))) void*)l, 16, 0, 0);
}

// ---------------- fused prep (weight transpose/cast) + GroupNorm stats ----------
// blocks [0,1024): weight transpose fp32[c][d] -> bf16[n][c], bias concat
// blocks [1024,1536): per-(b,g) stats -> per-channel affine coefs
//   coefA[b][c] = rstd*scale[c]; coefB[b][c] = bias[c] - mean*rstd*scale[c]
__global__ void prep_gn_kernel(const float* Wq, const float* Wk, const float* Wv,
                               const float* Wp, const float* bq, const float* bk,
                               const float* bv, unsigned short* wqkv_t,
                               unsigned short* wp_t, float* bqkv,
                               const float* x, const float* scale, const float* bias,
                               float* coefA, float* coefB) {
    int t = threadIdx.x;
    if (blockIdx.x < 1024) {
        int idx = blockIdx.x * 256 + t;
        if (idx < 768 * 256) {
            int n = idx >> 8, c = idx & 255;
            const float* W = (n < 256) ? Wq : (n < 512) ? Wk : Wv;
            int d = n & 255;
            wqkv_t[idx] = f2bf(W[c * 256 + d]);
        } else {
            int j = idx - 768 * 256;
            int n = j >> 8, c = j & 255;
            wp_t[j] = f2bf(Wp[c * 256 + n]);
        }
        if (idx < 768)
            bqkv[idx] = (idx < 256) ? bq[idx] : (idx < 512) ? bk[idx - 256] : bv[idx - 512];
    } else {
        int bg = blockIdx.x - 1024;               // b*32+g, group data contiguous
        const float4* p = reinterpret_cast<const float4*>(x + (size_t)bg * (CPG * HW));
        float s = 0.f, ss = 0.f;
        for (int i = t; i < CPG * HW / 4; i += 256) {
            float4 v = p[i];
            s += v.x + v.y + v.z + v.w;
            ss += v.x * v.x + v.y * v.y + v.z * v.z + v.w * v.w;
        }
        for (int o = 32; o; o >>= 1) { s += __shfl_down(s, o); ss += __shfl_down(ss, o); }
        __shared__ float as_[4], ass_[4];
        int w = t >> 6;
        if ((t & 63) == 0) { as_[w] = s; ass_[w] = ss; }
        __syncthreads();
        if (t < 8) {
            float S = as_[0] + as_[1] + as_[2] + as_[3];
            float SS = ass_[0] + ass_[1] + ass_[2] + ass_[3];
            float mean = S / (float)(CPG * HW);
            float var = SS / (float)(CPG * HW) - mean * mean;
            float rstd = rsqrtf(var + EPSV);
            int b = bg >> 5, g = bg & 31;
            int c = g * CPG + t;
            float a = rstd * scale[c];
            coefA[b * CH + c] = a;
            coefB[b * CH + c] = bias[c] - mean * a;
        }
    }
}

// ---------------- QKV GEMM with fused GroupNorm-apply ----------------------------
// 64(m) x 256(n) block tile, grid (256,3) -> 3 blocks/CU. Wave = 32x128.
// A-tile (64 p x 32 c) built in LDS from x directly: coalesced fp32 loads along p
// (register-prefetched one K-step ahead), fmaf normalize, RNE pair-pack to bf16,
// 16B slots XOR-swizzled by (p&3). A-build redundancy = 3x (was 6x at 128-wide N).
// B = wqkv_t[n][k] direct from global (L2-resident weights).
__global__ __launch_bounds__(256, 3) void qkv_kernel(const float* x,
        const float* coefA, const float* coefB,
        const unsigned short* wqkv_t, const float* bqkv,
        unsigned short* qb, unsigned short* kb, unsigned short* vb) {
    int t = threadIdx.x;
    int wv = t >> 6, lane = t & 63, quad = lane >> 4, ln = lane & 15;
    int wr = wv >> 1, wc = wv & 1;
    int bx = blockIdx.x;
    int m0 = bx * 64 + wr * 32;           // global m for epilogue
    int n0 = blockIdx.y * 256 + wc * 128;
    int bb = bx >> 4;                     // batch
    int p0 = (bx & 15) * 64;              // spatial base

    __shared__ __align__(16) unsigned short lds_a[64][40];  // 80B row stride, 16B-aligned

    const float* xb = x + (size_t)bb * CH * HW + p0;
    const float* cA = coefA + bb * CH;
    const float* cB = coefB + bb * CH;

    int sp = t & 63;                      // p within tile
    int slot = t >> 6;                    // 16B slot (0..3) == wave id

    // prefetch K-step 0's raw x values
    float xv[8];
#pragma unroll
    for (int j = 0; j < 8; j++)
        xv[j] = xb[(size_t)(slot * 8 + j) * HW + sp];

    f32x4 acc[2][8] = {};
    for (int k0 = 0; k0 < CH; k0 += 32) {
        int cb = k0 + slot * 8;
        union { bf16x8 v8; __hip_bfloat162 h2[4]; } u;
#pragma unroll
        for (int j = 0; j < 4; j++) {
            float v0 = fmaf(xv[2 * j],     cA[cb + 2 * j],     cB[cb + 2 * j]);
            float v1 = fmaf(xv[2 * j + 1], cA[cb + 2 * j + 1], cB[cb + 2 * j + 1]);
            u.h2[j] = __float22bfloat162_rn(float2{v0, v1});
        }
        // issue next K-step's strided loads early (hide latency under MFMA phase)
        if (k0 + 32 < CH) {
#pragma unroll
            for (int j = 0; j < 8; j++)
                xv[j] = xb[(size_t)(cb + 32 + j) * HW + sp];
        }
        // B-tile loads (L2-hot) issued before the barrier as well
        bf16x8 bfr[8];
#pragma unroll
        for (int j = 0; j < 8; j++)
            bfr[j] = *reinterpret_cast<const bf16x8*>(
                wqkv_t + (size_t)(n0 + j * 16 + ln) * CH + k0 + quad * 8);
        __syncthreads();                  // previous iter's fragment reads done
        int phys = slot ^ (sp & 3);
        *reinterpret_cast<bf16x8*>(&lds_a[sp][phys * 8]) = u.v8;
        __syncthreads();                  // tile visible
        bf16x8 af[2];
#pragma unroll
        for (int i = 0; i < 2; i++) {
            int p = wr * 32 + i * 16 + ln;
            af[i] = *reinterpret_cast<const bf16x8*>(&lds_a[p][(quad ^ (p & 3)) * 8]);
        }
#pragma unroll
        for (int i = 0; i < 2; i++)
#pragma unroll
            for (int j = 0; j < 8; j++)
                acc[i][j] = __builtin_amdgcn_mfma_f32_16x16x32_bf16(af[i], bfr[j], acc[i][j], 0, 0, 0);
    }
#pragma unroll
    for (int j = 0; j < 8; j++) {
        int n = n0 + j * 16 + ln;
        float bias = bqkv[n];
        int which = n >> 8;               // uniform per 16-tile
        int dh_ = n & 255;
        int head = dh_ >> 6, d = dh_ & 63;
#pragma unroll
        for (int i = 0; i < 2; i++) {
            int mb = m0 + i * 16 + quad * 4;
            int bi = mb >> 10, p = mb & 1023;
            int bh = bi * NH + head;
            if (which < 2) {
                unsigned short* dst = (which == 0 ? qb : kb) + (size_t)bh * HW * DH;
                float sc = (which == 0) ? QSCALE : 1.0f;
#pragma unroll
                for (int r = 0; r < 4; r++)
                    dst[(size_t)(p + r) * DH + d] = f2bf((acc[i][j][r] + bias) * sc);
            } else {
                unsigned short* dst = vb + ((size_t)bh * DH + d) * HW + p;
                ushort4 pk4;
                pk4.x = f2bf(acc[i][j][0] + bias);
                pk4.y = f2bf(acc[i][j][1] + bias);
                pk4.z = f2bf(acc[i][j][2] + bias);
                pk4.w = f2bf(acc[i][j][3] + bias);
                *reinterpret_cast<ushort4*>(dst) = pk4;
            }
        }
    }
}

// ---------------- attention: LDS-staged K/V, 32 q/wave, unroll-2 pipeline ---------
__global__ __launch_bounds__(256) void attn_kernel(const unsigned short* qb,
        const unsigned short* kb, const unsigned short* vb, unsigned short* h_t) {
    int qblk = blockIdx.x, bh = blockIdx.y;
    int t = threadIdx.x;
    int wv = t >> 6, lane = t & 63, quad = lane >> 4, ln = lane & 15;
    int q0 = qblk * 128 + wv * 32;

    const unsigned short* Q = qb + (size_t)bh * HW * DH;
    const unsigned short* K = kb + (size_t)bh * HW * DH;
    const unsigned short* V = vb + (size_t)bh * DH * HW;

    __shared__ __align__(16) unsigned short kbuf[2][4096];   // [p][swizzled 16B chunks]
    __shared__ __align__(16) unsigned short vbuf[2][4096];
    __shared__ __align__(16) unsigned short pbuf[4][2][16][72];

    // staging: chunk c -> row p = c>>3, stored slot (c&7), holding global chunk (c&7)^(p&7)
    int c_a = wv * 64 + lane;
    int c_b = 256 + wv * 64 + lane;
    int pa = c_a >> 3, ja = (c_a & 7) ^ (pa & 7);
    int pb = c_b >> 3, jb = (c_b & 7) ^ (pb & 7);
    const unsigned short* pka = K + (size_t)pa * DH + ja * 8;
    const unsigned short* pkb = K + (size_t)pb * DH + jb * 8;
    const unsigned short* pva = V + (size_t)pa * HW + ja * 8;
    const unsigned short* pvb = V + (size_t)pb * HW + jb * 8;
    int lofs_a = wv * 512, lofs_b = 2048 + wv * 512;

    // loop-invariant LDS fragment offsets (ushort units)
    int koffs[4][2];
#pragma unroll
    for (int mt = 0; mt < 4; mt++) {
        int p = mt * 16 + ln, sw = p & 7;
#pragma unroll
        for (int kk = 0; kk < 2; kk++)
            koffs[mt][kk] = p * 64 + (((kk * 4 + quad) ^ sw) * 8);
    }

    bf16x8 qf[2][2];
#pragma unroll
    for (int nq = 0; nq < 2; nq++)
#pragma unroll
        for (int kk = 0; kk < 2; kk++)
            qf[nq][kk] = *reinterpret_cast<const bf16x8*>(
                Q + (size_t)(q0 + nq * 16 + ln) * DH + kk * 32 + quad * 8);

    f32x4 ls[2] = {};
    f32x4 o[2][4] = {};

    // prologue: stage tile 0 into buffer 0
    gld_lds16(pka, &kbuf[0][lofs_a]);
    gld_lds16(pkb, &kbuf[0][lofs_b]);
    gld_lds16(pva, &vbuf[0][lofs_a]);
    gld_lds16(pvb, &vbuf[0][lofs_b]);
    pka += 64 * DH; pkb += 64 * DH; pva += 64; pvb += 64;

#define ATTN_TILE(B, DO_STAGE)                                                      \
    {                                                                               \
        __syncthreads();                                                            \
        if (DO_STAGE) {                                                             \
            gld_lds16(pka, &kbuf[B ^ 1][lofs_a]);                                   \
            gld_lds16(pkb, &kbuf[B ^ 1][lofs_b]);                                   \
            gld_lds16(pva, &vbuf[B ^ 1][lofs_a]);                                   \
            gld_lds16(pvb, &vbuf[B ^ 1][lofs_b]);                                   \
            pka += 64 * DH; pkb += 64 * DH; pva += 64; pvb += 64;                   \
        }                                                                           \
        bf16x8 kf[4][2], vf[4][2];                                                  \
        _Pragma("unroll")                                                           \
        for (int mt = 0; mt < 4; mt++) {                                            \
            _Pragma("unroll")                                                       \
            for (int kk = 0; kk < 2; kk++) {                                        \
                kf[mt][kk] = *reinterpret_cast<const bf16x8*>(&kbuf[B][koffs[mt][kk]]); \
                vf[mt][kk] = *reinterpret_cast<const bf16x8*>(&vbuf[B][koffs[mt][kk]]); \
            }                                                                       \
        }                                                                           \
        f32x4 s[2][4] = {};                                                         \
        __builtin_amdgcn_s_setprio(1);                                              \
        _Pragma("unroll")                                                           \
        for (int nq = 0; nq < 2; nq++)                                              \
            _Pragma("unroll")                                                       \
            for (int mt = 0; mt < 4; mt++) {                                        \
                s[nq][mt] = __builtin_amdgcn_mfma_f32_16x16x32_bf16(kf[mt][0], qf[nq][0], s[nq][mt], 0, 0, 0); \
                s[nq][mt] = __builtin_amdgcn_mfma_f32_16x16x32_bf16(kf[mt][1], qf[nq][1], s[nq][mt], 0, 0, 0); \
            }                                                                       \
        __builtin_amdgcn_s_setprio(0);                                              \
        _Pragma("unroll")                                                           \
        for (int nq = 0; nq < 2; nq++)                                              \
            _Pragma("unroll")                                                       \
            for (int mt = 0; mt < 4; mt++) {                                        \
                float e0 = __builtin_amdgcn_exp2f(s[nq][mt][0]);                    \
                float e1 = __builtin_amdgcn_exp2f(s[nq][mt][1]);                    \
                float e2 = __builtin_amdgcn_exp2f(s[nq][mt][2]);                    \
                float e3 = __builtin_amdgcn_exp2f(s[nq][mt][3]);                    \
                ls[nq][0] += e0; ls[nq][1] += e1;                                   \
                ls[nq][2] += e2; ls[nq][3] += e3;                                   \
                uint2 pk2;                                                          \
                pk2.x = __builtin_amdgcn_perm(fbits(e1), fbits(e0), 0x07060302u);   \
                pk2.y = __builtin_amdgcn_perm(fbits(e3), fbits(e2), 0x07060302u);   \
                *reinterpret_cast<uint2*>(&pbuf[wv][nq][ln][mt * 16 + quad * 4]) = pk2; \
            }                                                                       \
        _Pragma("unroll")                                                           \
        for (int nq = 0; nq < 2; nq++)                                              \
            _Pragma("unroll")                                                       \
            for (int kk = 0; kk < 2; kk++) {                                        \
                bf16x8 pf = *reinterpret_cast<const bf16x8*>(&pbuf[wv][nq][ln][kk * 32 + quad * 8]); \
                __builtin_amdgcn_s_setprio(1);                                      \
                _Pragma("unroll")                                                   \
                for (int mt = 0; mt < 4; mt++)                                      \
                    o[nq][mt] = __builtin_amdgcn_mfma_f32_16x16x32_bf16(vf[mt][kk], pf, o[nq][mt], 0, 0, 0); \
                __builtin_amdgcn_s_setprio(0);                                      \
            }                                                                       \
    }

    for (int u = 0; u < 8; u++) {
        ATTN_TILE(0, true)            // compute tile 2u,   stage tile 2u+1
        ATTN_TILE(1, (u < 7))         // compute tile 2u+1, stage tile 2u+2
    }
#undef ATTN_TILE

    int b_ = bh >> 2, head = bh & 3;
#pragma unroll
    for (int nq = 0; nq < 2; nq++) {
        float lsum = ls[nq][0] + ls[nq][1] + ls[nq][2] + ls[nq][3];
        lsum += __shfl_xor(lsum, 16);
        lsum += __shfl_xor(lsum, 32);
        float inv = 1.0f / lsum;
        unsigned short* dst = h_t + ((size_t)b_ * HW + q0 + nq * 16 + ln) * CH + head * DH;
#pragma unroll
        for (int mt = 0; mt < 4; mt++) {
            ushort4 pk4;
            pk4.x = f2bf(o[nq][mt][0] * inv);
            pk4.y = f2bf(o[nq][mt][1] * inv);
            pk4.z = f2bf(o[nq][mt][2] * inv);
            pk4.w = f2bf(o[nq][mt][3] * inv);
            *reinterpret_cast<ushort4*>(dst + mt * 16 + quad * 4) = pk4;
        }
    }
}

// ---------------- proj GEMM + bias + residual + /sqrt(2) -------------------------
// 64x128 block tile (512 blocks -> 2 blocks/CU), 32x64 per wave.
__global__ __launch_bounds__(256) void proj_kernel(const unsigned short* h_t,
        const unsigned short* wp_t, const float* bp, const float* x, float* out) {
    int t = threadIdx.x;
    int wv = t >> 6, lane = t & 63, quad = lane >> 4, ln = lane & 15;
    int wr = wv >> 1, wc = wv & 1;
    int m0 = blockIdx.x * 64 + wr * 32;
    int n0 = blockIdx.y * 128 + wc * 64;

    f32x4 acc[2][4] = {};
    for (int k0 = 0; k0 < CH; k0 += 32) {
        int koff = k0 + quad * 8;
        bf16x8 af[2], bfr[4];
#pragma unroll
        for (int i = 0; i < 2; i++)
            af[i] = *reinterpret_cast<const bf16x8*>(h_t + (size_t)(m0 + i * 16 + ln) * CH + koff);
#pragma unroll
        for (int j = 0; j < 4; j++)
            bfr[j] = *reinterpret_cast<const bf16x8*>(wp_t + (size_t)(n0 + j * 16 + ln) * CH + koff);
#pragma unroll
        for (int i = 0; i < 2; i++)
#pragma unroll
            for (int j = 0; j < 4; j++)
                acc[i][j] = __builtin_amdgcn_mfma_f32_16x16x32_bf16(af[i], bfr[j], acc[i][j], 0, 0, 0);
    }
    const float inv_s2 = 0.70710678118654752440f;
#pragma unroll
    for (int j = 0; j < 4; j++) {
        int n = n0 + j * 16 + ln;
        float bias = bp[n];
#pragma unroll
        for (int i = 0; i < 2; i++) {
            int mb = m0 + i * 16 + quad * 4;
            int bi = mb >> 10, p = mb & 1023;
            size_t off = ((size_t)(bi * CH + n)) * HW + p;
            float4 xv = *reinterpret_cast<const float4*>(x + off);
            float4 ov;
            ov.x = (xv.x + acc[i][j][0] + bias) * inv_s2;
            ov.y = (xv.y + acc[i][j][1] + bias) * inv_s2;
            ov.z = (xv.z + acc[i][j][2] + bias) * inv_s2;
            ov.w = (xv.w + acc[i][j][3] + bias) * inv_s2;
            *reinterpret_cast<float4*>(out + off) = ov;
        }
    }
}

extern "C" void kernel_launch(void* const* d_in, const int* in_sizes, int n_in,
                              void* d_out, int out_size, void* d_ws, size_t ws_size,
                              hipStream_t stream) {
    const float* x        = (const float*)d_in[0];
    const float* gn_scale = (const float*)d_in[1];
    const float* gn_bias  = (const float*)d_in[2];
    const float* Wq = (const float*)d_in[3];
    const float* bq = (const float*)d_in[4];
    const float* Wk = (const float*)d_in[5];
    const float* bk = (const float*)d_in[6];
    const float* Wv = (const float*)d_in[7];
    const float* bv = (const float*)d_in[8];
    const float* Wp = (const float*)d_in[9];
    const float* bp = (const float*)d_in[10];
    float* out = (float*)d_out;

    char* ws = (char*)d_ws;
    // ws layout (bytes), total ~34.6 MB
    float*          bqkv   = (float*)(ws + 0);            // 768 f
    float*          coefA  = (float*)(ws + 4096);         // 16*256 f
    float*          coefB  = (float*)(ws + 20480);        // 16*256 f
    unsigned short* wqkv_t = (unsigned short*)(ws + 36864);    // 393216 B
    unsigned short* wp_t   = (unsigned short*)(ws + 430080);   // 131072 B
    unsigned short* h_t    = (unsigned short*)(ws + 1048576);  // 8.39 MB
    unsigned short* qb     = (unsigned short*)(ws + 9437184);
    unsigned short* kb     = (unsigned short*)(ws + 17825792);
    unsigned short* vb     = (unsigned short*)(ws + 26214400);

    prep_gn_kernel<<<1536, 256, 0, stream>>>(Wq, Wk, Wv, Wp, bq, bk, bv,
                                             wqkv_t, wp_t, bqkv,
                                             x, gn_scale, gn_bias, coefA, coefB);
    qkv_kernel<<<dim3(256, 3), 256, 0, stream>>>(x, coefA, coefB, wqkv_t, bqkv, qb, kb, vb);
    attn_kernel<<<dim3(8, 64), 256, 0, stream>>>(qb, kb, vb, h_t);
    proj_kernel<<<dim3(256, 2), 256, 0, stream>>>(h_t, wp_t, bp, x, out);
}

// Round 2
// 165.447 us; speedup vs baseline: 1.0448x; 1.0448x over previous
//
#include <hip/hip_runtime.h>
#include <hip/hip_bf16.h>

#define BATCH 16
#define CH    256
#define HW    1024
#define NH    4
#define DH    64
#define NG    32
#define CPG   8
#define EPSV  1e-6f

// log2(e) / sqrt(C) folded into Q so softmax = exp2(S_scaled)
#define QSCALE 0.090168440055558706f

typedef __bf16 bf16x8 __attribute__((ext_vector_type(8)));
typedef float  f32x4  __attribute__((ext_vector_type(4)));

__device__ __forceinline__ unsigned short f2bf(float f) {
    union { __hip_bfloat16 h; unsigned short u; } cv;
    cv.h = __float2bfloat16(f);
    return cv.u;
}

__device__ __forceinline__ unsigned int fbits(float f) {
    union { float f; unsigned int u; } cv; cv.f = f; return cv.u;
}

__device__ __forceinline__ void gld_lds16(const unsigned short* g, unsigned short* l) {
    __builtin_amdgcn_global_load_lds(
        (const __attribute__((address_space(1))) void*)g,
        (__attribute__((address_space(3))) void*)l, 16, 0, 0);
}

// ---------------- fused prep (weight transpose/cast) + GroupNorm stats+apply -----
// blocks [0,1024): weight transpose fp32[c][d] -> bf16[n][c], bias concat
// blocks [1024,1536): per-(b,g) stats, then normalize-apply writing xn[b][p][c] bf16.
// Key: the stats loads of thread t are exactly the (8c x 4p) block the apply needs,
// so the apply re-reads nothing — coefs broadcast via LDS, pack in-register.
__global__ void prep_gn_kernel(const float* Wq, const float* Wk, const float* Wv,
                               const float* Wp, const float* bq, const float* bk,
                               const float* bv, unsigned short* wqkv_t,
                               unsigned short* wp_t, float* bqkv,
                               const float* x, const float* scale, const float* bias,
                               unsigned short* xn) {
    int t = threadIdx.x;
    if (blockIdx.x < 1024) {
        int idx = blockIdx.x * 256 + t;
        if (idx < 768 * 256) {
            int n = idx >> 8, c = idx & 255;
            const float* W = (n < 256) ? Wq : (n < 512) ? Wk : Wv;
            int d = n & 255;
            wqkv_t[idx] = f2bf(W[c * 256 + d]);
        } else {
            int j = idx - 768 * 256;
            int n = j >> 8, c = j & 255;
            wp_t[j] = f2bf(Wp[c * 256 + n]);
        }
        if (idx < 768)
            bqkv[idx] = (idx < 256) ? bq[idx] : (idx < 512) ? bk[idx - 256] : bv[idx - 512];
    } else {
        int bg = blockIdx.x - 1024;               // b*32+g, group data contiguous
        const float4* p = reinterpret_cast<const float4*>(x + (size_t)bg * (CPG * HW));
        float va[8][4];                            // [c][p_local], all indices static
        float s = 0.f, ss = 0.f;
#pragma unroll
        for (int k = 0; k < 8; k++) {
            float4 v = p[t + 256 * k];            // (c = k, p = t*4..t*4+4)
            va[k][0] = v.x; va[k][1] = v.y; va[k][2] = v.z; va[k][3] = v.w;
            s += v.x + v.y + v.z + v.w;
            ss += v.x * v.x + v.y * v.y + v.z * v.z + v.w * v.w;
        }
        for (int o = 32; o; o >>= 1) { s += __shfl_down(s, o); ss += __shfl_down(ss, o); }
        __shared__ float as_[4], ass_[4];
        __shared__ float sA[8], sB[8];
        int w = t >> 6;
        if ((t & 63) == 0) { as_[w] = s; ass_[w] = ss; }
        __syncthreads();
        if (t < 8) {
            float S = as_[0] + as_[1] + as_[2] + as_[3];
            float SS = ass_[0] + ass_[1] + ass_[2] + ass_[3];
            float mean = S / (float)(CPG * HW);
            float var = SS / (float)(CPG * HW) - mean * mean;
            float rstd = rsqrtf(var + EPSV);
            int g = bg & 31;
            int c = g * CPG + t;
            float a = rstd * scale[c];
            sA[t] = a;
            sB[t] = bias[c] - mean * a;
        }
        __syncthreads();
        int b = bg >> 5, g = bg & 31;
        unsigned short* dst = xn + ((size_t)b * HW + t * 4) * CH + g * CPG;
#pragma unroll
        for (int pl = 0; pl < 4; pl++) {
            union { bf16x8 v8; __hip_bfloat162 h2[4]; } u;
#pragma unroll
            for (int c2 = 0; c2 < 4; c2++) {
                float v0 = fmaf(va[2 * c2][pl],     sA[2 * c2],     sB[2 * c2]);
                float v1 = fmaf(va[2 * c2 + 1][pl], sA[2 * c2 + 1], sB[2 * c2 + 1]);
                u.h2[c2] = __float22bfloat162_rn(float2{v0, v1});
            }
            *reinterpret_cast<bf16x8*>(dst + (size_t)pl * CH) = u.v8;
        }
    }
}

// ---------------- QKV GEMM: pure direct-load GEMM (proj-structure) ---------------
// A = xn[m][c] bf16 (m = b*1024+p), fragment loads are 16 rows x one 64B line each
// (fully line-coalesced, L2-resident). B = wqkv_t[n][k]. No LDS, no barriers.
// 128x128 block tile, 64x64 per wave, grid (128, 6) -> 3 blocks/CU.
__global__ __launch_bounds__(256) void qkv_kernel(const unsigned short* xn,
        const unsigned short* wqkv_t, const float* bqkv,
        unsigned short* qb, unsigned short* kb, unsigned short* vb) {
    int t = threadIdx.x;
    int wv = t >> 6, lane = t & 63, quad = lane >> 4, ln = lane & 15;
    int wr = wv >> 1, wc = wv & 1;
    int m0 = blockIdx.x * 128 + wr * 64;
    int n0 = blockIdx.y * 128 + wc * 64;

    f32x4 acc[4][4] = {};
    for (int k0 = 0; k0 < CH; k0 += 32) {
        int koff = k0 + quad * 8;
        bf16x8 af[4], bfr[4];
#pragma unroll
        for (int i = 0; i < 4; i++)
            af[i] = *reinterpret_cast<const bf16x8*>(
                xn + (size_t)(m0 + i * 16 + ln) * CH + koff);
#pragma unroll
        for (int j = 0; j < 4; j++)
            bfr[j] = *reinterpret_cast<const bf16x8*>(
                wqkv_t + (size_t)(n0 + j * 16 + ln) * CH + koff);
#pragma unroll
        for (int i = 0; i < 4; i++)
#pragma unroll
            for (int j = 0; j < 4; j++)
                acc[i][j] = __builtin_amdgcn_mfma_f32_16x16x32_bf16(af[i], bfr[j], acc[i][j], 0, 0, 0);
    }
#pragma unroll
    for (int j = 0; j < 4; j++) {
        int n = n0 + j * 16 + ln;
        float bias = bqkv[n];
        int which = n >> 8;               // uniform per 16-tile
        int dh_ = n & 255;
        int head = dh_ >> 6, d = dh_ & 63;
#pragma unroll
        for (int i = 0; i < 4; i++) {
            int mb = m0 + i * 16 + quad * 4;
            int bi = mb >> 10, p = mb & 1023;
            int bh = bi * NH + head;
            if (which < 2) {
                unsigned short* dst = (which == 0 ? qb : kb) + (size_t)bh * HW * DH;
                float sc = (which == 0) ? QSCALE : 1.0f;
#pragma unroll
                for (int r = 0; r < 4; r++)
                    dst[(size_t)(p + r) * DH + d] = f2bf((acc[i][j][r] + bias) * sc);
            } else {
                unsigned short* dst = vb + ((size_t)bh * DH + d) * HW + p;
                ushort4 pk4;
                pk4.x = f2bf(acc[i][j][0] + bias);
                pk4.y = f2bf(acc[i][j][1] + bias);
                pk4.z = f2bf(acc[i][j][2] + bias);
                pk4.w = f2bf(acc[i][j][3] + bias);
                *reinterpret_cast<ushort4*>(dst) = pk4;
            }
        }
    }
}

// ---------------- attention: LDS-staged K/V, 32 q/wave, unroll-2 pipeline ---------
__global__ __launch_bounds__(256) void attn_kernel(const unsigned short* qb,
        const unsigned short* kb, const unsigned short* vb, unsigned short* h_t) {
    int qblk = blockIdx.x, bh = blockIdx.y;
    int t = threadIdx.x;
    int wv = t >> 6, lane = t & 63, quad = lane >> 4, ln = lane & 15;
    int q0 = qblk * 128 + wv * 32;

    const unsigned short* Q = qb + (size_t)bh * HW * DH;
    const unsigned short* K = kb + (size_t)bh * HW * DH;
    const unsigned short* V = vb + (size_t)bh * DH * HW;

    __shared__ __align__(16) unsigned short kbuf[2][4096];   // [p][swizzled 16B chunks]
    __shared__ __align__(16) unsigned short vbuf[2][4096];
    __shared__ __align__(16) unsigned short pbuf[4][2][16][72];

    // staging: chunk c -> row p = c>>3, stored slot (c&7), holding global chunk (c&7)^(p&7)
    int c_a = wv * 64 + lane;
    int c_b = 256 + wv * 64 + lane;
    int pa = c_a >> 3, ja = (c_a & 7) ^ (pa & 7);
    int pb = c_b >> 3, jb = (c_b & 7) ^ (pb & 7);
    const unsigned short* pka = K + (size_t)pa * DH + ja * 8;
    const unsigned short* pkb = K + (size_t)pb * DH + jb * 8;
    const unsigned short* pva = V + (size_t)pa * HW + ja * 8;
    const unsigned short* pvb = V + (size_t)pb * HW + jb * 8;
    int lofs_a = wv * 512, lofs_b = 2048 + wv * 512;

    // loop-invariant LDS fragment offsets (ushort units)
    int koffs[4][2];
#pragma unroll
    for (int mt = 0; mt < 4; mt++) {
        int p = mt * 16 + ln, sw = p & 7;
#pragma unroll
        for (int kk = 0; kk < 2; kk++)
            koffs[mt][kk] = p * 64 + (((kk * 4 + quad) ^ sw) * 8);
    }

    bf16x8 qf[2][2];
#pragma unroll
    for (int nq = 0; nq < 2; nq++)
#pragma unroll
        for (int kk = 0; kk < 2; kk++)
            qf[nq][kk] = *reinterpret_cast<const bf16x8*>(
                Q + (size_t)(q0 + nq * 16 + ln) * DH + kk * 32 + quad * 8);

    f32x4 ls[2] = {};
    f32x4 o[2][4] = {};

    // prologue: stage tile 0 into buffer 0
    gld_lds16(pka, &kbuf[0][lofs_a]);
    gld_lds16(pkb, &kbuf[0][lofs_b]);
    gld_lds16(pva, &vbuf[0][lofs_a]);
    gld_lds16(pvb, &vbuf[0][lofs_b]);
    pka += 64 * DH; pkb += 64 * DH; pva += 64; pvb += 64;

#define ATTN_TILE(B, DO_STAGE)                                                      \
    {                                                                               \
        __syncthreads();                                                            \
        if (DO_STAGE) {                                                             \
            gld_lds16(pka, &kbuf[B ^ 1][lofs_a]);                                   \
            gld_lds16(pkb, &kbuf[B ^ 1][lofs_b]);                                   \
            gld_lds16(pva, &vbuf[B ^ 1][lofs_a]);                                   \
            gld_lds16(pvb, &vbuf[B ^ 1][lofs_b]);                                   \
            pka += 64 * DH; pkb += 64 * DH; pva += 64; pvb += 64;                   \
        }                                                                           \
        bf16x8 kf[4][2], vf[4][2];                                                  \
        _Pragma("unroll")                                                           \
        for (int mt = 0; mt < 4; mt++) {                                            \
            _Pragma("unroll")                                                       \
            for (int kk = 0; kk < 2; kk++) {                                        \
                kf[mt][kk] = *reinterpret_cast<const bf16x8*>(&kbuf[B][koffs[mt][kk]]); \
                vf[mt][kk] = *reinterpret_cast<const bf16x8*>(&vbuf[B][koffs[mt][kk]]); \
            }                                                                       \
        }                                                                           \
        f32x4 s[2][4] = {};                                                         \
        _Pragma("unroll")                                                           \
        for (int nq = 0; nq < 2; nq++)                                              \
            _Pragma("unroll")                                                       \
            for (int mt = 0; mt < 4; mt++) {                                        \
                s[nq][mt] = __builtin_amdgcn_mfma_f32_16x16x32_bf16(kf[mt][0], qf[nq][0], s[nq][mt], 0, 0, 0); \
                s[nq][mt] = __builtin_amdgcn_mfma_f32_16x16x32_bf16(kf[mt][1], qf[nq][1], s[nq][mt], 0, 0, 0); \
            }                                                                       \
        _Pragma("unroll")                                                           \
        for (int nq = 0; nq < 2; nq++)                                              \
            _Pragma("unroll")                                                       \
            for (int mt = 0; mt < 4; mt++) {                                        \
                float e0 = __builtin_amdgcn_exp2f(s[nq][mt][0]);                    \
                float e1 = __builtin_amdgcn_exp2f(s[nq][mt][1]);                    \
                float e2 = __builtin_amdgcn_exp2f(s[nq][mt][2]);                    \
                float e3 = __builtin_amdgcn_exp2f(s[nq][mt][3]);                    \
                ls[nq][0] += e0; ls[nq][1] += e1;                                   \
                ls[nq][2] += e2; ls[nq][3] += e3;                                   \
                uint2 pk2;                                                          \
                pk2.x = __builtin_amdgcn_perm(fbits(e1), fbits(e0), 0x07060302u);   \
                pk2.y = __builtin_amdgcn_perm(fbits(e3), fbits(e2), 0x07060302u);   \
                *reinterpret_cast<uint2*>(&pbuf[wv][nq][ln][mt * 16 + quad * 4]) = pk2; \
            }                                                                       \
        _Pragma("unroll")                                                           \
        for (int nq = 0; nq < 2; nq++)                                              \
            _Pragma("unroll")                                                       \
            for (int kk = 0; kk < 2; kk++) {                                        \
                bf16x8 pf = *reinterpret_cast<const bf16x8*>(&pbuf[wv][nq][ln][kk * 32 + quad * 8]); \
                _Pragma("unroll")                                                   \
                for (int mt = 0; mt < 4; mt++)                                      \
                    o[nq][mt] = __builtin_amdgcn_mfma_f32_16x16x32_bf16(vf[mt][kk], pf, o[nq][mt], 0, 0, 0); \
            }                                                                       \
    }

    for (int u = 0; u < 8; u++) {
        ATTN_TILE(0, true)            // compute tile 2u,   stage tile 2u+1
        ATTN_TILE(1, (u < 7))         // compute tile 2u+1, stage tile 2u+2
    }
#undef ATTN_TILE

    int b_ = bh >> 2, head = bh & 3;
#pragma unroll
    for (int nq = 0; nq < 2; nq++) {
        float lsum = ls[nq][0] + ls[nq][1] + ls[nq][2] + ls[nq][3];
        lsum += __shfl_xor(lsum, 16);
        lsum += __shfl_xor(lsum, 32);
        float inv = 1.0f / lsum;
        unsigned short* dst = h_t + ((size_t)b_ * HW + q0 + nq * 16 + ln) * CH + head * DH;
#pragma unroll
        for (int mt = 0; mt < 4; mt++) {
            ushort4 pk4;
            pk4.x = f2bf(o[nq][mt][0] * inv);
            pk4.y = f2bf(o[nq][mt][1] * inv);
            pk4.z = f2bf(o[nq][mt][2] * inv);
            pk4.w = f2bf(o[nq][mt][3] * inv);
            *reinterpret_cast<ushort4*>(dst + mt * 16 + quad * 4) = pk4;
        }
    }
}

// ---------------- proj GEMM + bias + residual + /sqrt(2) -------------------------
// 64x128 block tile (512 blocks -> 2 blocks/CU), 32x64 per wave.
__global__ __launch_bounds__(256) void proj_kernel(const unsigned short* h_t,
        const unsigned short* wp_t, const float* bp, const float* x, float* out) {
    int t = threadIdx.x;
    int wv = t >> 6, lane = t & 63, quad = lane >> 4, ln = lane & 15;
    int wr = wv >> 1, wc = wv & 1;
    int m0 = blockIdx.x * 64 + wr * 32;
    int n0 = blockIdx.y * 128 + wc * 64;

    f32x4 acc[2][4] = {};
    for (int k0 = 0; k0 < CH; k0 += 32) {
        int koff = k0 + quad * 8;
        bf16x8 af[2], bfr[4];
#pragma unroll
        for (int i = 0; i < 2; i++)
            af[i] = *reinterpret_cast<const bf16x8*>(h_t + (size_t)(m0 + i * 16 + ln) * CH + koff);
#pragma unroll
        for (int j = 0; j < 4; j++)
            bfr[j] = *reinterpret_cast<const bf16x8*>(wp_t + (size_t)(n0 + j * 16 + ln) * CH + koff);
#pragma unroll
        for (int i = 0; i < 2; i++)
#pragma unroll
            for (int j = 0; j < 4; j++)
                acc[i][j] = __builtin_amdgcn_mfma_f32_16x16x32_bf16(af[i], bfr[j], acc[i][j], 0, 0, 0);
    }
    const float inv_s2 = 0.70710678118654752440f;
#pragma unroll
    for (int j = 0; j < 4; j++) {
        int n = n0 + j * 16 + ln;
        float bias = bp[n];
#pragma unroll
        for (int i = 0; i < 2; i++) {
            int mb = m0 + i * 16 + quad * 4;
            int bi = mb >> 10, p = mb & 1023;
            size_t off = ((size_t)(bi * CH + n)) * HW + p;
            float4 xv = *reinterpret_cast<const float4*>(x + off);
            float4 ov;
            ov.x = (xv.x + acc[i][j][0] + bias) * inv_s2;
            ov.y = (xv.y + acc[i][j][1] + bias) * inv_s2;
            ov.z = (xv.z + acc[i][j][2] + bias) * inv_s2;
            ov.w = (xv.w + acc[i][j][3] + bias) * inv_s2;
            *reinterpret_cast<float4*>(out + off) = ov;
        }
    }
}

extern "C" void kernel_launch(void* const* d_in, const int* in_sizes, int n_in,
                              void* d_out, int out_size, void* d_ws, size_t ws_size,
                              hipStream_t stream) {
    const float* x        = (const float*)d_in[0];
    const float* gn_scale = (const float*)d_in[1];
    const float* gn_bias  = (const float*)d_in[2];
    const float* Wq = (const float*)d_in[3];
    const float* bq = (const float*)d_in[4];
    const float* Wk = (const float*)d_in[5];
    const float* bk = (const float*)d_in[6];
    const float* Wv = (const float*)d_in[7];
    const float* bv = (const float*)d_in[8];
    const float* Wp = (const float*)d_in[9];
    const float* bp = (const float*)d_in[10];
    float* out = (float*)d_out;

    char* ws = (char*)d_ws;
    // ws layout (bytes), total ~43 MB
    float*          bqkv   = (float*)(ws + 0);                 // 768 f
    unsigned short* wqkv_t = (unsigned short*)(ws + 36864);    // 393216 B
    unsigned short* wp_t   = (unsigned short*)(ws + 430080);   // 131072 B
    unsigned short* xn     = (unsigned short*)(ws + 1048576);  // 8.39 MB bf16 [16][1024][256]
    unsigned short* h_t    = (unsigned short*)(ws + 9437184);  // 8.39 MB
    unsigned short* qb     = (unsigned short*)(ws + 17825792);
    unsigned short* kb     = (unsigned short*)(ws + 26214400);
    unsigned short* vb     = (unsigned short*)(ws + 34603008);

    prep_gn_kernel<<<1536, 256, 0, stream>>>(Wq, Wk, Wv, Wp, bq, bk, bv,
                                             wqkv_t, wp_t, bqkv,
                                             x, gn_scale, gn_bias, xn);
    qkv_kernel<<<dim3(128, 6), 256, 0, stream>>>(xn, wqkv_t, bqkv, qb, kb, vb);
    attn_kernel<<<dim3(8, 64), 256, 0, stream>>>(qb, kb, vb, h_t);
    proj_kernel<<<dim3(256, 2), 256, 0, stream>>>(h_t, wp_t, bp, x, out);
}